// Round 12
// baseline (244.049 us; speedup 1.0000x reference)
//
#include <hip/hip_runtime.h>

#define B_ 4
#define C_ 256
#define N_ 4096
#define E_ 32

typedef _Float16 f16x8 __attribute__((ext_vector_type(8)));
typedef _Float16 f16x4 __attribute__((ext_vector_type(4)));
typedef _Float16 f16x2 __attribute__((ext_vector_type(2)));
typedef float f32x4 __attribute__((ext_vector_type(4)));

#define LOG2E 1.44269504088896f
#define EXP2(x) __builtin_amdgcn_exp2f(x)
// cvt_pkrtz returns __fp16x2; bit-identical to f16x2 — bit_cast is free
#define PKRTZ(a, b) __builtin_bit_cast(f16x2, __builtin_amdgcn_cvt_pkrtz((a), (b)))

// LDS column swizzle: breaks bank conflicts of row-strided b128 reads while
// keeping 16B alignment (swizzle unit = 8 f16 = 16 B; same on write & read).
#define XSWZ(row, col) ((col) ^ ((((row) >> 2) & 7) << 3))

// ---------------------------------------------------------------------------
// Kernel 1 (UNCHANGED from R17, passing @122.3): 512 blocks x 256 thr,
// n-tile 32, 2 blocks/CU. Frozen so Δtotal attributes to attn.
// ---------------------------------------------------------------------------
__global__ __launch_bounds__(256) void proj_kernel(
    const float* __restrict__ x,
    const float* __restrict__ Wk, const float* __restrict__ bk,
    const float* __restrict__ Wq, const float* __restrict__ bq,
    const float* __restrict__ Wv, const float* __restrict__ bv,
    const float* __restrict__ Wo,
    _Float16* __restrict__ Qb, _Float16* __restrict__ Kb, _Float16* __restrict__ Vt,
    _Float16* __restrict__ Wof16, float* __restrict__ out)
{
    const int b  = blockIdx.x >> 7;          // 128 blocks per batch
    const int n0 = (blockIdx.x & 127) << 5;  // n-tile of 32
    const int t    = threadIdx.x;
    const int lane = t & 63;
    const int wave = t >> 6;
    const int l15  = lane & 15;
    const int quad = lane >> 4;

    // distributed Wo convert: blocks 0..255 each convert one Wo row
    if (blockIdx.x < 256 && t < 8) {
        float4 wv = ((const float4*)(Wo + blockIdx.x * E_))[t];
        f16x4 tp = {(_Float16)wv.x, (_Float16)wv.y, (_Float16)wv.z, (_Float16)wv.w};
        *(f16x4*)&Wof16[blockIdx.x * E_ + t * 4] = tp;
    }
    if (blockIdx.x == 0 && t == 0)
        out[(size_t)2 * B_ * C_ * N_] = 0.5f;   // gamma (non-learned)

    __shared__ _Float16 xT[32][264];   // x tile transposed [n_local][c], XSWZ'd
    __shared__ _Float16 Wl[32][264];   // current matrix's weights [e][c], XSWZ'd
    __shared__ _Float16 vT[32][44];    // V transpose staging [e][n_local]

    for (int i4 = t; i4 < (32 * 256) / 4; i4 += 256) {
        int j4 = (i4 & 7) * 4;
        int c  = i4 >> 3;
        float4 xv = *(const float4*)(x + (size_t)(b * C_ + c) * N_ + n0 + j4);
        xT[j4 + 0][XSWZ(j4 + 0, c)] = (_Float16)xv.x;
        xT[j4 + 1][XSWZ(j4 + 1, c)] = (_Float16)xv.y;
        xT[j4 + 2][XSWZ(j4 + 2, c)] = (_Float16)xv.z;
        xT[j4 + 3][XSWZ(j4 + 3, c)] = (_Float16)xv.w;
    }

    const float* Ws[3] = {Wk, Wq, Wv};
    const float* bs[3] = {bk, bq, bv};

    const int rowg = wave >> 1;            // n half (0/1)
    const int et   = wave & 1;             // e half (0/1)
    const int row  = rowg * 16 + l15;
    f16x8 Bf[8];

    for (int m = 0; m < 3; ++m) {
        for (int i4 = t; i4 < (E_ * C_) / 4; i4 += 256) {
            float4 wv = ((const float4*)Ws[m])[i4];
            int e = (i4 * 4) >> 8, c = (i4 * 4) & 255;
            f16x4 tp = {(_Float16)wv.x, (_Float16)wv.y, (_Float16)wv.z, (_Float16)wv.w};
            *(f16x4*)&Wl[e][XSWZ(e, c)] = tp;
        }
        __syncthreads();
        if (m == 0) {
            #pragma unroll
            for (int kk = 0; kk < 8; ++kk)
                Bf[kk] = *(const f16x8*)&xT[row][XSWZ(row, kk * 32 + quad * 8)];
        }
        const float sc = (m == 1) ? LOG2E : 1.0f;
        const float* bias = bs[m];
        f32x4 acc = {0.f, 0.f, 0.f, 0.f};
        #pragma unroll
        for (int kk = 0; kk < 8; ++kk) {
            const int e = et * 16 + l15;
            f16x8 Af = *(const f16x8*)&Wl[e][XSWZ(e, kk * 32 + quad * 8)];
            acc = __builtin_amdgcn_mfma_f32_16x16x32_f16(Af, Bf[kk], acc, 0, 0, 0);
        }
        const int n  = n0 + row;
        const int e0 = et * 16 + quad * 4;
        if (m == 2) {
            #pragma unroll
            for (int r = 0; r < 4; ++r)
                vT[e0 + r][row] = (_Float16)(acc[r] + bias[e0 + r]);
        } else {
            f16x4 st;
            #pragma unroll
            for (int r = 0; r < 4; ++r)
                st[r] = (_Float16)((acc[r] + bias[e0 + r]) * sc);
            _Float16* dst = (m == 0) ? Kb : Qb;
            *(f16x4*)&dst[(size_t)(b * N_ + n) * E_ + e0] = st;
        }
        __syncthreads();
    }

    // cooperative V store: exactly one Vt tile (2 KB), 128 threads x f16x8
    if (t < 128) {
        const int e_s = t >> 2;            // 0..31
        const int nb  = t & 3;             // 0..3 (8 n's each)
        f16x8 v = *(const f16x8*)&vT[e_s][nb * 8];
        size_t base = ((size_t)(b * 128 + (n0 >> 5)) * 32 + e_s) * 32 + nb * 8;
        *(f16x8*)&Vt[base] = v;
    }
}

// ---------------------------------------------------------------------------
// Kernel 2 (R20): flash attention + fused output projection.
// R19 post-mortem: j-16 output tiles split 128B cache lines across blocks
// on different XCDs -> cross-XCD RMW ping-pong (WRITE 33->196 MB, FETCH
// 17->63 MB, attn 100us). LESSON: block output tiles must cover whole
// 128B lines (j >= 32 for f32).
// R20: j-tile 32 restored (R18 traffic), occupancy doubled the safe way:
// 1024-thread blocks = 16 waves, wave = (cg, ig): cg = col group (16 j),
// ig = i-split (512 keys). Each wave runs R19's proven single-col loop
// (KVBLK 64, folded-C softmax, PKRTZ, affine prefetch). Grid 512 = 2
// blocks/CU -> 32 waves/CU = 8 waves/SIMD (was 4). ~41 KB LDS/block;
// loop measured 40 VGPR (R19) <= the 64 cap from launch_bounds(1024,8).
// ---------------------------------------------------------------------------
__global__ __launch_bounds__(1024, 8) void attn_kernel(
    const _Float16* __restrict__ Qb, const _Float16* __restrict__ Kb,
    const _Float16* __restrict__ Vt, const _Float16* __restrict__ Wof16,
    const float* __restrict__ bo, const float* __restrict__ x,
    float* __restrict__ out)
{
    const int wave = threadIdx.x >> 6;     // 0..15
    const int ig   = wave & 7;             // i-split (512 keys each)
    const int cg   = wave >> 3;            // col group 0/1
    const int lane = threadIdx.x & 63;
    const int l15  = lane & 15, quad = lane >> 4;
    const int jg   = blockIdx.x;           // 0..511
    const int b    = jg >> 7;
    const int j0   = (jg & 127) << 5;      // j-tile of 32
    const int jcol = j0 + cg * 16;         // this wave's 16 columns

    // per-wave 2304B: loop = P bounce [16][72] f16 (keys 0..63);
    // epilogue = osum [16][34] f32 overlay (barrier-separated).
    __shared__ __align__(16) char big[16][2304];          // 36.9 KB
    __shared__ float    mls[16][2][16];                   // 2 KB
    __shared__ _Float16 Om[2][16][40];                    // 2.5 KB

    f16x8 Qf = *(const f16x8*)(Qb + (size_t)(b * N_ + jcol + l15) * E_ + quad * 8);

    f32x4 O0 = {0, 0, 0, 0}, O1 = {0, 0, 0, 0};
    float mneg = 0.f, lsum = 0.f;          // mneg = -mrow (MFMA C seed)

    const _Float16* Kp = Kb + (size_t)b * N_ * E_ + (size_t)(ig << 9) * E_;
    const _Float16* Vp = Vt + ((size_t)(b * 128 + ig * 16) << 10);

    // prologue loads (keys 0..63 of this wave's range)
    f16x8 K0 = *(const f16x8*)(Kp + (size_t)(l15) * E_ + quad * 8);
    f16x8 K1 = *(const f16x8*)(Kp + (size_t)(16 + l15) * E_ + quad * 8);
    f16x8 K2 = *(const f16x8*)(Kp + (size_t)(32 + l15) * E_ + quad * 8);
    f16x8 K3 = *(const f16x8*)(Kp + (size_t)(48 + l15) * E_ + quad * 8);
    f16x8 Va0 = *(const f16x8*)(Vp + l15 * 32 + quad * 8);
    f16x8 Vc0 = *(const f16x8*)(Vp + (16 + l15) * 32 + quad * 8);
    f16x8 Va1 = *(const f16x8*)(Vp + 1024 + l15 * 32 + quad * 8);
    f16x8 Vc1 = *(const f16x8*)(Vp + 1024 + (16 + l15) * 32 + quad * 8);

    for (int it = 0; it < 8; ++it) {
        const int i0n = (it + 1) << 6;     // affine; last-iter over-read lands
                                           // in allocated ws (harmless)
        f32x4 S0, S1, S2, S3;
        {
            f32x4 c0 = {mneg, mneg, mneg, mneg};
            __builtin_amdgcn_s_setprio(1);
            S0 = __builtin_amdgcn_mfma_f32_16x16x32_f16(K0, Qf, c0, 0, 0, 0);
            S1 = __builtin_amdgcn_mfma_f32_16x16x32_f16(K1, Qf, c0, 0, 0, 0);
            S2 = __builtin_amdgcn_mfma_f32_16x16x32_f16(K2, Qf, c0, 0, 0, 0);
            S3 = __builtin_amdgcn_mfma_f32_16x16x32_f16(K3, Qf, c0, 0, 0, 0);
            __builtin_amdgcn_s_setprio(0);
        }
        // prefetch next iteration's K (same SSA names)
        K0 = *(const f16x8*)(Kp + (size_t)(i0n + l15) * E_ + quad * 8);
        K1 = *(const f16x8*)(Kp + (size_t)(i0n + 16 + l15) * E_ + quad * 8);
        K2 = *(const f16x8*)(Kp + (size_t)(i0n + 32 + l15) * E_ + quad * 8);
        K3 = *(const f16x8*)(Kp + (size_t)(i0n + 48 + l15) * E_ + quad * 8);

        // ---- softmax (S' is already S - mrow via the C-operand fold) ----
        {
            float t0 = fmaxf(fmaxf(S0[0], S0[1]), S0[2]);
            float t1 = fmaxf(fmaxf(S0[3], S1[0]), S1[1]);
            float t2 = fmaxf(fmaxf(S1[2], S1[3]), S2[0]);
            float t3 = fmaxf(fmaxf(S2[1], S2[2]), S2[3]);
            float t4 = fmaxf(fmaxf(S3[0], S3[1]), S3[2]);
            float mxl = fmaxf(fmaxf(fmaxf(t0, t1), t2),
                              fmaxf(fmaxf(t3, t4), S3[3]));
            if (__any(mxl > 8.f)) {        // trigger: reduce, ratchet, rescale
                float mx = fmaxf(mxl, __shfl_xor(mxl, 16));
                mx = fmaxf(mx, __shfl_xor(mx, 32));
                float mc = fmaxf(mx, 0.f); // reference only moves up
                float alpha = EXP2(-mc);
                mneg -= mc;
                lsum *= alpha;
                O0 *= alpha;
                O1 *= alpha;
                #pragma unroll
                for (int r = 0; r < 4; ++r) {
                    S0[r] -= mc; S1[r] -= mc; S2[r] -= mc; S3[r] -= mc;
                }
            }
            float p0  = EXP2(S0[0]), p1  = EXP2(S0[1]);
            float p2  = EXP2(S0[2]), p3  = EXP2(S0[3]);
            float p4  = EXP2(S1[0]), p5  = EXP2(S1[1]);
            float p6  = EXP2(S1[2]), p7  = EXP2(S1[3]);
            float p8  = EXP2(S2[0]), p9  = EXP2(S2[1]);
            float p10 = EXP2(S2[2]), p11 = EXP2(S2[3]);
            float p12 = EXP2(S3[0]), p13 = EXP2(S3[1]);
            float p14 = EXP2(S3[2]), p15 = EXP2(S3[3]);
            lsum += (((p0 + p1) + (p2 + p3)) + ((p4 + p5) + (p6 + p7)))
                  + (((p8 + p9) + (p10 + p11)) + ((p12 + p13) + (p14 + p15)));

            f16x2 a0 = PKRTZ(p0,  p1),  a1 = PKRTZ(p2,  p3);
            f16x2 a2 = PKRTZ(p4,  p5),  a3 = PKRTZ(p6,  p7);
            f16x2 a4 = PKRTZ(p8,  p9),  a5 = PKRTZ(p10, p11);
            f16x2 a6 = PKRTZ(p12, p13), a7 = PKRTZ(p14, p15);
            f16x4 wA0 = {a0[0], a0[1], a1[0], a1[1]};
            f16x4 wA1 = {a2[0], a2[1], a3[0], a3[1]};
            f16x4 wB0 = {a4[0], a4[1], a5[0], a5[1]};
            f16x4 wB1 = {a6[0], a6[1], a7[0], a7[1]};
            _Float16 (*pb)[72] = (_Float16 (*)[72])(big[wave]);
            *(f16x4*)&pb[l15][quad * 4]      = wA0;
            *(f16x4*)&pb[l15][16 + quad * 4] = wA1;
            *(f16x4*)&pb[l15][32 + quad * 4] = wB0;
            *(f16x4*)&pb[l15][48 + quad * 4] = wB1;
        }
        // ---- P reads + PV MFMAs ----
        f16x8 PA, PB;
        {
            _Float16 (*pb)[72] = (_Float16 (*)[72])(big[wave]);
            PA = *(const f16x8*)&pb[l15][quad * 8];
            PB = *(const f16x8*)&pb[l15][32 + quad * 8];
        }
        __builtin_amdgcn_s_setprio(1);
        O0 = __builtin_amdgcn_mfma_f32_16x16x32_f16(Va0, PA, O0, 0, 0, 0);
        O1 = __builtin_amdgcn_mfma_f32_16x16x32_f16(Vc0, PA, O1, 0, 0, 0);
        O0 = __builtin_amdgcn_mfma_f32_16x16x32_f16(Va1, PB, O0, 0, 0, 0);
        O1 = __builtin_amdgcn_mfma_f32_16x16x32_f16(Vc1, PB, O1, 0, 0, 0);
        __builtin_amdgcn_s_setprio(0);
        // prefetch next iteration's V (tiled layout: two 2KB tiles)
        Va0 = *(const f16x8*)(Vp + (i0n << 5) + l15 * 32 + quad * 8);
        Vc0 = *(const f16x8*)(Vp + (i0n << 5) + (16 + l15) * 32 + quad * 8);
        Va1 = *(const f16x8*)(Vp + (i0n << 5) + 1024 + l15 * 32 + quad * 8);
        Vc1 = *(const f16x8*)(Vp + (i0n << 5) + 1024 + (16 + l15) * 32 + quad * 8);
    }

    // publish per-split (m, l)  (mrow = -mneg)
    {
        float ls = lsum;
        ls += __shfl_xor(ls, 16);
        ls += __shfl_xor(ls, 32);
        if (quad == 0) { mls[wave][0][l15] = -mneg; mls[wave][1][l15] = ls; }
    }
    __syncthreads();

    // LSE combine within this wave's col group (8 splits: waves cg*8 + s)
    {
        float M = -1e30f, ms[8], ls[8];
        #pragma unroll
        for (int s = 0; s < 8; ++s) {
            ms[s] = mls[cg * 8 + s][0][l15]; ls[s] = mls[cg * 8 + s][1][l15];
            M = fmaxf(M, ms[s]);
        }
        float L = 0.f;
        #pragma unroll
        for (int s = 0; s < 8; ++s) L += ls[s] * EXP2(ms[s] - M);
        const float w = EXP2(-mneg - M) / L;
        float (*osum)[34] = (float (*)[34])(big[wave]);
        *(f32x4*)&osum[l15][quad * 4]      = O0 * w;
        *(f32x4*)&osum[l15][16 + quad * 4] = O1 * w;
    }
    __syncthreads();

    // cross-split sum -> merged O rows (f16); one thread per (cc, j, e)
    {
        const int cc = threadIdx.x >> 9;        // 0/1
        const int j  = (threadIdx.x >> 5) & 15; // 0..15
        const int e  = threadIdx.x & 31;        // 0..31
        float a = 0.f;
        #pragma unroll
        for (int s = 0; s < 8; ++s)
            a += ((const float (*)[34])(big[cc * 8 + s]))[j][e];
        Om[cc][j][e] = (_Float16)a;
    }
    __syncthreads();

    // ---- fused output projection: each wave covers 16 channels x 2 cols ----
    f16x8 Bf2[2];
    #pragma unroll
    for (int cc = 0; cc < 2; ++cc)
        Bf2[cc] = *(const f16x8*)&Om[cc][l15][quad * 8];
    float* out_y = out + (size_t)b * C_ * N_;
    float* out_o = out + (size_t)B_ * C_ * N_ + (size_t)b * C_ * N_;
    const float* xb = x + (size_t)b * C_ * N_;
    {
        const int c0 = wave * 16;
        f16x8 Af = *(const f16x8*)(Wof16 + (size_t)(c0 + l15) * E_ + quad * 8);
        f32x4 acc[2];
        f32x4 z = {0, 0, 0, 0};
        #pragma unroll
        for (int cc = 0; cc < 2; ++cc)
            acc[cc] = __builtin_amdgcn_mfma_f32_16x16x32_f16(Af, Bf2[cc], z, 0, 0, 0);
        #pragma unroll
        for (int r = 0; r < 4; ++r) {
            const int c = c0 + quad * 4 + r;
            #pragma unroll
            for (int cc = 0; cc < 2; ++cc) {
                size_t idx = (size_t)c * N_ + j0 + cc * 16 + l15;
                float ov = acc[cc][r] + bo[c];
                out_o[idx] = ov;
                out_y[idx] = 0.5f * ov + xb[idx];
            }
        }
    }
}

// ---------------------------------------------------------------------------
extern "C" void kernel_launch(void* const* d_in, const int* in_sizes, int n_in,
                              void* d_out, int out_size, void* d_ws, size_t ws_size,
                              hipStream_t stream)
{
    const float* x  = (const float*)d_in[0];
    const float* Wk = (const float*)d_in[1];
    const float* bk = (const float*)d_in[2];
    const float* Wq = (const float*)d_in[3];
    const float* bq = (const float*)d_in[4];
    const float* Wv = (const float*)d_in[5];
    const float* bv = (const float*)d_in[6];
    const float* Wo = (const float*)d_in[7];
    const float* bo = (const float*)d_in[8];
    float* out = (float*)d_out;

    char* ws = (char*)d_ws;
    _Float16* Qb    = (_Float16*)(ws);                   // 1 MB  [B][N][E]
    _Float16* Kb    = (_Float16*)(ws + (1u << 20));      // 1 MB  [B][N][E]
    _Float16* Vt    = (_Float16*)(ws + (2u << 20));      // 1 MB  [B][N/32][E][32]
    _Float16* Wof16 = (_Float16*)(ws + (3u << 20));      // 16 KB [C][E]

    // 512 proj blocks (n-tile 32, 2 blocks/CU; x read once)
    proj_kernel<<<dim3(512), dim3(256), 0, stream>>>(
        x, Wk, bk, Wq, bq, Wv, bv, Wo, Qb, Kb, Vt, Wof16, out);
    // 512 attn blocks x 1024 threads: j-tile 32, 16 waves (2 col x 8 split),
    // 2 blocks/CU -> 8 waves/SIMD
    attn_kernel<<<dim3(B_ * (N_ / 32)), dim3(1024), 0, stream>>>(
        Qb, Kb, Vt, Wof16, bo, x, out);
}

// Round 13
// 120.207 us; speedup vs baseline: 2.0302x; 2.0302x over previous
//
#include <hip/hip_runtime.h>

#define B_ 4
#define C_ 256
#define N_ 4096
#define E_ 32

typedef _Float16 f16x8 __attribute__((ext_vector_type(8)));
typedef _Float16 f16x4 __attribute__((ext_vector_type(4)));
typedef _Float16 f16x2 __attribute__((ext_vector_type(2)));
typedef float f32x4 __attribute__((ext_vector_type(4)));

#define LOG2E 1.44269504088896f
#define EXP2(x) __builtin_amdgcn_exp2f(x)
// cvt_pkrtz returns __fp16x2; bit-identical to f16x2 — bit_cast is free
#define PKRTZ(a, b) __builtin_bit_cast(f16x2, __builtin_amdgcn_cvt_pkrtz((a), (b)))

// LDS column swizzle: breaks bank conflicts of row-strided b128 reads while
// keeping 16B alignment (swizzle unit = 8 f16 = 16 B; same on write & read).
#define XSWZ(row, col) ((col) ^ ((((row) >> 2) & 7) << 3))

// ---------------------------------------------------------------------------
// Kernel 1 (R17 structure, best-measured): 512 blocks x 256 thr, n-tile 32,
// 2 blocks/CU; x staged once; V written in tiled layout Vt[b][n/32][e][n%32];
// Wo-convert distributed one row per block.
// ---------------------------------------------------------------------------
__global__ __launch_bounds__(256) void proj_kernel(
    const float* __restrict__ x,
    const float* __restrict__ Wk, const float* __restrict__ bk,
    const float* __restrict__ Wq, const float* __restrict__ bq,
    const float* __restrict__ Wv, const float* __restrict__ bv,
    const float* __restrict__ Wo,
    _Float16* __restrict__ Qb, _Float16* __restrict__ Kb, _Float16* __restrict__ Vt,
    _Float16* __restrict__ Wof16, float* __restrict__ out)
{
    const int b  = blockIdx.x >> 7;          // 128 blocks per batch
    const int n0 = (blockIdx.x & 127) << 5;  // n-tile of 32
    const int t    = threadIdx.x;
    const int lane = t & 63;
    const int wave = t >> 6;
    const int l15  = lane & 15;
    const int quad = lane >> 4;

    // distributed Wo convert: blocks 0..255 each convert one Wo row
    if (blockIdx.x < 256 && t < 8) {
        float4 wv = ((const float4*)(Wo + blockIdx.x * E_))[t];
        f16x4 tp = {(_Float16)wv.x, (_Float16)wv.y, (_Float16)wv.z, (_Float16)wv.w};
        *(f16x4*)&Wof16[blockIdx.x * E_ + t * 4] = tp;
    }
    if (blockIdx.x == 0 && t == 0)
        out[(size_t)2 * B_ * C_ * N_] = 0.5f;   // gamma (non-learned)

    __shared__ _Float16 xT[32][264];   // x tile transposed [n_local][c], XSWZ'd
    __shared__ _Float16 Wl[32][264];   // current matrix's weights [e][c], XSWZ'd
    __shared__ _Float16 vT[32][44];    // V transpose staging [e][n_local]

    for (int i4 = t; i4 < (32 * 256) / 4; i4 += 256) {
        int j4 = (i4 & 7) * 4;
        int c  = i4 >> 3;
        float4 xv = *(const float4*)(x + (size_t)(b * C_ + c) * N_ + n0 + j4);
        xT[j4 + 0][XSWZ(j4 + 0, c)] = (_Float16)xv.x;
        xT[j4 + 1][XSWZ(j4 + 1, c)] = (_Float16)xv.y;
        xT[j4 + 2][XSWZ(j4 + 2, c)] = (_Float16)xv.z;
        xT[j4 + 3][XSWZ(j4 + 3, c)] = (_Float16)xv.w;
    }

    const float* Ws[3] = {Wk, Wq, Wv};
    const float* bs[3] = {bk, bq, bv};

    const int rowg = wave >> 1;            // n half (0/1)
    const int et   = wave & 1;             // e half (0/1)
    const int row  = rowg * 16 + l15;
    f16x8 Bf[8];

    for (int m = 0; m < 3; ++m) {
        for (int i4 = t; i4 < (E_ * C_) / 4; i4 += 256) {
            float4 wv = ((const float4*)Ws[m])[i4];
            int e = (i4 * 4) >> 8, c = (i4 * 4) & 255;
            f16x4 tp = {(_Float16)wv.x, (_Float16)wv.y, (_Float16)wv.z, (_Float16)wv.w};
            *(f16x4*)&Wl[e][XSWZ(e, c)] = tp;
        }
        __syncthreads();
        if (m == 0) {
            #pragma unroll
            for (int kk = 0; kk < 8; ++kk)
                Bf[kk] = *(const f16x8*)&xT[row][XSWZ(row, kk * 32 + quad * 8)];
        }
        const float sc = (m == 1) ? LOG2E : 1.0f;
        const float* bias = bs[m];
        f32x4 acc = {0.f, 0.f, 0.f, 0.f};
        #pragma unroll
        for (int kk = 0; kk < 8; ++kk) {
            const int e = et * 16 + l15;
            f16x8 Af = *(const f16x8*)&Wl[e][XSWZ(e, kk * 32 + quad * 8)];
            acc = __builtin_amdgcn_mfma_f32_16x16x32_f16(Af, Bf[kk], acc, 0, 0, 0);
        }
        const int n  = n0 + row;
        const int e0 = et * 16 + quad * 4;
        if (m == 2) {
            #pragma unroll
            for (int r = 0; r < 4; ++r)
                vT[e0 + r][row] = (_Float16)(acc[r] + bias[e0 + r]);
        } else {
            f16x4 st;
            #pragma unroll
            for (int r = 0; r < 4; ++r)
                st[r] = (_Float16)((acc[r] + bias[e0 + r]) * sc);
            _Float16* dst = (m == 0) ? Kb : Qb;
            *(f16x4*)&dst[(size_t)(b * N_ + n) * E_ + e0] = st;
        }
        __syncthreads();
    }

    // cooperative V store: exactly one Vt tile (2 KB), 128 threads x f16x8
    if (t < 128) {
        const int e_s = t >> 2;            // 0..31
        const int nb  = t & 3;             // 0..3 (8 n's each)
        f16x8 v = *(const f16x8*)&vT[e_s][nb * 8];
        size_t base = ((size_t)(b * 128 + (n0 >> 5)) * 32 + e_s) * 32 + nb * 8;
        *(f16x8*)&Vt[base] = v;
    }
}

// ---------------------------------------------------------------------------
// Kernel 2 (R18, best-measured @122.27us — byte-exact revert).
// R20 post-mortem: 16-wave blocks + launch_bounds(1024,8) halved the VGPR
// budget (64) below the loop's ~75-reg live set -> allocator landed at 32
// VGPR -> scratch spill every iteration (FETCH 220MB / WRITE 434MB,
// VALUBusy 8%, attn 155us). With R19's cache-line lesson this CLOSES the
// occupancy ladder both ways: smaller j-tiles split 128B output lines
// across XCDs; more waves/CU starve registers. j-32 / KVBLK-64 / 512-thr /
// 2-blocks-per-CU / 40-VGPR is the constrained optimum of this structure.
// ---------------------------------------------------------------------------
__global__ __launch_bounds__(512, 4) void attn_kernel(
    const _Float16* __restrict__ Qb, const _Float16* __restrict__ Kb,
    const _Float16* __restrict__ Vt, const _Float16* __restrict__ Wof16,
    const float* __restrict__ bo, const float* __restrict__ x,
    float* __restrict__ out)
{
    const int wave = threadIdx.x >> 6;     // i-split 0..7 (512 keys each)
    const int lane = threadIdx.x & 63;
    const int l15  = lane & 15, quad = lane >> 4;
    const int jg   = blockIdx.x;           // 0..511
    const int b    = jg >> 7;
    const int j0   = (jg & 127) << 5;      // j-tile of 32

    // per-wave, per-col 2304B: loop = P bounce [16][72] f16 (keys 0..63);
    // epilogue = osum [16][34] f32 overlay (barrier-separated).
    __shared__ __align__(16) char big[8][2][2304];        // 36.9 KB
    __shared__ float    mls[8][2][2][16];
    __shared__ _Float16 Om[2][16][40];

    f16x8 Qf[2];
    #pragma unroll
    for (int cc = 0; cc < 2; ++cc)
        Qf[cc] = *(const f16x8*)(Qb + (size_t)(b * N_ + j0 + cc * 16 + l15) * E_ + quad * 8);

    f32x4 O0c[2], O1c[2];
    float mneg[2], lsum[2];                // mneg = -mrow (seed value)
    #pragma unroll
    for (int cc = 0; cc < 2; ++cc) {
        O0c[cc] = (f32x4){0, 0, 0, 0}; O1c[cc] = (f32x4){0, 0, 0, 0};
        mneg[cc] = 0.f; lsum[cc] = 0.f;
    }

    const _Float16* Kp = Kb + (size_t)b * N_ * E_ + (size_t)(wave << 9) * E_;
    const _Float16* Vp = Vt + ((size_t)(b * 128 + wave * 16) << 10);

    // prologue loads (keys 0..63 of this wave's range)
    f16x8 K0 = *(const f16x8*)(Kp + (size_t)(l15) * E_ + quad * 8);
    f16x8 K1 = *(const f16x8*)(Kp + (size_t)(16 + l15) * E_ + quad * 8);
    f16x8 K2 = *(const f16x8*)(Kp + (size_t)(32 + l15) * E_ + quad * 8);
    f16x8 K3 = *(const f16x8*)(Kp + (size_t)(48 + l15) * E_ + quad * 8);
    f16x8 Va0 = *(const f16x8*)(Vp + l15 * 32 + quad * 8);
    f16x8 Vc0 = *(const f16x8*)(Vp + (16 + l15) * 32 + quad * 8);
    f16x8 Va1 = *(const f16x8*)(Vp + 1024 + l15 * 32 + quad * 8);
    f16x8 Vc1 = *(const f16x8*)(Vp + 1024 + (16 + l15) * 32 + quad * 8);

    for (int it = 0; it < 8; ++it) {
        const int i0n = (it + 1) << 6;     // affine; last-iter over-read lands
                                           // in allocated ws (harmless)
        f32x4 S[2][4];
        {
            f32x4 c0 = {mneg[0], mneg[0], mneg[0], mneg[0]};
            f32x4 c1 = {mneg[1], mneg[1], mneg[1], mneg[1]};
            __builtin_amdgcn_s_setprio(1);
            S[0][0] = __builtin_amdgcn_mfma_f32_16x16x32_f16(K0, Qf[0], c0, 0, 0, 0);
            S[0][1] = __builtin_amdgcn_mfma_f32_16x16x32_f16(K1, Qf[0], c0, 0, 0, 0);
            S[0][2] = __builtin_amdgcn_mfma_f32_16x16x32_f16(K2, Qf[0], c0, 0, 0, 0);
            S[0][3] = __builtin_amdgcn_mfma_f32_16x16x32_f16(K3, Qf[0], c0, 0, 0, 0);
            S[1][0] = __builtin_amdgcn_mfma_f32_16x16x32_f16(K0, Qf[1], c1, 0, 0, 0);
            S[1][1] = __builtin_amdgcn_mfma_f32_16x16x32_f16(K1, Qf[1], c1, 0, 0, 0);
            S[1][2] = __builtin_amdgcn_mfma_f32_16x16x32_f16(K2, Qf[1], c1, 0, 0, 0);
            S[1][3] = __builtin_amdgcn_mfma_f32_16x16x32_f16(K3, Qf[1], c1, 0, 0, 0);
            __builtin_amdgcn_s_setprio(0);
        }
        // prefetch next iteration's K (same SSA names)
        K0 = *(const f16x8*)(Kp + (size_t)(i0n + l15) * E_ + quad * 8);
        K1 = *(const f16x8*)(Kp + (size_t)(i0n + 16 + l15) * E_ + quad * 8);
        K2 = *(const f16x8*)(Kp + (size_t)(i0n + 32 + l15) * E_ + quad * 8);
        K3 = *(const f16x8*)(Kp + (size_t)(i0n + 48 + l15) * E_ + quad * 8);

        // ---- phase A: softmax both cols (S' is already S - mrow) ----
        #pragma unroll
        for (int cc = 0; cc < 2; ++cc) {
            // max over 16 in-lane scores (max3-shaped)
            float t0 = fmaxf(fmaxf(S[cc][0][0], S[cc][0][1]), S[cc][0][2]);
            float t1 = fmaxf(fmaxf(S[cc][0][3], S[cc][1][0]), S[cc][1][1]);
            float t2 = fmaxf(fmaxf(S[cc][1][2], S[cc][1][3]), S[cc][2][0]);
            float t3 = fmaxf(fmaxf(S[cc][2][1], S[cc][2][2]), S[cc][2][3]);
            float t4 = fmaxf(fmaxf(S[cc][3][0], S[cc][3][1]), S[cc][3][2]);
            float mxl = fmaxf(fmaxf(fmaxf(t0, t1), t2),
                              fmaxf(fmaxf(t3, t4), S[cc][3][3]));
            if (__any(mxl > 8.f)) {        // trigger: reduce, ratchet, rescale
                float mx = fmaxf(mxl, __shfl_xor(mxl, 16));
                mx = fmaxf(mx, __shfl_xor(mx, 32));
                float mc = fmaxf(mx, 0.f); // reference only moves up
                float alpha = EXP2(-mc);
                mneg[cc] -= mc;
                lsum[cc] *= alpha;
                O0c[cc] *= alpha;
                O1c[cc] *= alpha;
                #pragma unroll
                for (int kt = 0; kt < 4; ++kt)
                    #pragma unroll
                    for (int r = 0; r < 4; ++r)
                        S[cc][kt][r] -= mc;   // rare path only
            }
            float p0  = EXP2(S[cc][0][0]), p1  = EXP2(S[cc][0][1]);
            float p2  = EXP2(S[cc][0][2]), p3  = EXP2(S[cc][0][3]);
            float p4  = EXP2(S[cc][1][0]), p5  = EXP2(S[cc][1][1]);
            float p6  = EXP2(S[cc][1][2]), p7  = EXP2(S[cc][1][3]);
            float p8  = EXP2(S[cc][2][0]), p9  = EXP2(S[cc][2][1]);
            float p10 = EXP2(S[cc][2][2]), p11 = EXP2(S[cc][2][3]);
            float p12 = EXP2(S[cc][3][0]), p13 = EXP2(S[cc][3][1]);
            float p14 = EXP2(S[cc][3][2]), p15 = EXP2(S[cc][3][3]);
            lsum[cc] += (((p0 + p1) + (p2 + p3)) + ((p4 + p5) + (p6 + p7)))
                      + (((p8 + p9) + (p10 + p11)) + ((p12 + p13) + (p14 + p15)));

            f16x2 a0 = PKRTZ(p0,  p1),  a1 = PKRTZ(p2,  p3);
            f16x2 a2 = PKRTZ(p4,  p5),  a3 = PKRTZ(p6,  p7);
            f16x2 a4 = PKRTZ(p8,  p9),  a5 = PKRTZ(p10, p11);
            f16x2 a6 = PKRTZ(p12, p13), a7 = PKRTZ(p14, p15);
            f16x4 wA0 = {a0[0], a0[1], a1[0], a1[1]};   // tile 0 (keys 4q+r)
            f16x4 wA1 = {a2[0], a2[1], a3[0], a3[1]};   // tile 1
            f16x4 wB0 = {a4[0], a4[1], a5[0], a5[1]};   // tile 2
            f16x4 wB1 = {a6[0], a6[1], a7[0], a7[1]};   // tile 3
            _Float16 (*pb)[72] = (_Float16 (*)[72])(big[wave][cc]);
            *(f16x4*)&pb[l15][quad * 4]      = wA0;
            *(f16x4*)&pb[l15][16 + quad * 4] = wA1;
            *(f16x4*)&pb[l15][32 + quad * 4] = wB0;
            *(f16x4*)&pb[l15][48 + quad * 4] = wB1;
        }
        // ---- phase B: P reads + PV MFMAs ----
        f16x8 PA0, PB0, PA1, PB1;
        {
            _Float16 (*pb0)[72] = (_Float16 (*)[72])(big[wave][0]);
            _Float16 (*pb1)[72] = (_Float16 (*)[72])(big[wave][1]);
            PA0 = *(const f16x8*)&pb0[l15][quad * 8];
            PB0 = *(const f16x8*)&pb0[l15][32 + quad * 8];
            PA1 = *(const f16x8*)&pb1[l15][quad * 8];
            PB1 = *(const f16x8*)&pb1[l15][32 + quad * 8];
        }
        __builtin_amdgcn_s_setprio(1);
        O0c[0] = __builtin_amdgcn_mfma_f32_16x16x32_f16(Va0, PA0, O0c[0], 0, 0, 0);
        O1c[0] = __builtin_amdgcn_mfma_f32_16x16x32_f16(Vc0, PA0, O1c[0], 0, 0, 0);
        O0c[1] = __builtin_amdgcn_mfma_f32_16x16x32_f16(Va0, PA1, O0c[1], 0, 0, 0);
        O1c[1] = __builtin_amdgcn_mfma_f32_16x16x32_f16(Vc0, PA1, O1c[1], 0, 0, 0);
        O0c[0] = __builtin_amdgcn_mfma_f32_16x16x32_f16(Va1, PB0, O0c[0], 0, 0, 0);
        O1c[0] = __builtin_amdgcn_mfma_f32_16x16x32_f16(Vc1, PB0, O1c[0], 0, 0, 0);
        O0c[1] = __builtin_amdgcn_mfma_f32_16x16x32_f16(Va1, PB1, O0c[1], 0, 0, 0);
        O1c[1] = __builtin_amdgcn_mfma_f32_16x16x32_f16(Vc1, PB1, O1c[1], 0, 0, 0);
        __builtin_amdgcn_s_setprio(0);
        // prefetch next iteration's V (tiled layout: two 2KB tiles)
        Va0 = *(const f16x8*)(Vp + (i0n << 5) + l15 * 32 + quad * 8);
        Vc0 = *(const f16x8*)(Vp + (i0n << 5) + (16 + l15) * 32 + quad * 8);
        Va1 = *(const f16x8*)(Vp + (i0n << 5) + 1024 + l15 * 32 + quad * 8);
        Vc1 = *(const f16x8*)(Vp + (i0n << 5) + 1024 + (16 + l15) * 32 + quad * 8);
    }

    // publish per-split (m, l) for both cols (mrow = -mneg)
    #pragma unroll
    for (int cc = 0; cc < 2; ++cc) {
        float ls = lsum[cc];
        ls += __shfl_xor(ls, 16);
        ls += __shfl_xor(ls, 32);
        if (quad == 0) { mls[wave][0][cc][l15] = -mneg[cc]; mls[wave][1][cc][l15] = ls; }
    }
    __syncthreads();

    // LSE combine + osum write, per col
    #pragma unroll
    for (int cc = 0; cc < 2; ++cc) {
        float M = -1e30f, ms[8], ls[8];
        #pragma unroll
        for (int s = 0; s < 8; ++s) {
            ms[s] = mls[s][0][cc][l15]; ls[s] = mls[s][1][cc][l15];
            M = fmaxf(M, ms[s]);
        }
        float L = 0.f;
        #pragma unroll
        for (int s = 0; s < 8; ++s) L += ls[s] * EXP2(ms[s] - M);
        const float w = EXP2(-mneg[cc] - M) / L;
        float (*osum)[34] = (float (*)[34])(big[wave][cc]);
        *(f32x4*)&osum[l15][quad * 4]      = O0c[cc] * w;
        *(f32x4*)&osum[l15][16 + quad * 4] = O1c[cc] * w;
    }
    __syncthreads();

    // cross-split sum -> merged O rows (f16); one thread per (j, e), x2 cols
    {
        const int j = threadIdx.x >> 5;    // 0..15
        const int e = threadIdx.x & 31;    // 0..31
        #pragma unroll
        for (int cc = 0; cc < 2; ++cc) {
            float a = 0.f;
            #pragma unroll
            for (int s = 0; s < 8; ++s)
                a += ((const float (*)[34])(big[s][cc]))[j][e];
            Om[cc][j][e] = (_Float16)a;
        }
    }
    __syncthreads();

    // ---- fused output projection: each wave covers 32 channels x 2 cols ----
    f16x8 Bf2[2];
    #pragma unroll
    for (int cc = 0; cc < 2; ++cc)
        Bf2[cc] = *(const f16x8*)&Om[cc][l15][quad * 8];
    float* out_y = out + (size_t)b * C_ * N_;
    float* out_o = out + (size_t)B_ * C_ * N_ + (size_t)b * C_ * N_;
    const float* xb = x + (size_t)b * C_ * N_;
    #pragma unroll
    for (int ct = 0; ct < 2; ++ct) {
        const int c0 = wave * 32 + ct * 16;
        f16x8 Af = *(const f16x8*)(Wof16 + (size_t)(c0 + l15) * E_ + quad * 8);
        f32x4 acc[2];
        f32x4 z = {0, 0, 0, 0};
        #pragma unroll
        for (int cc = 0; cc < 2; ++cc)
            acc[cc] = __builtin_amdgcn_mfma_f32_16x16x32_f16(Af, Bf2[cc], z, 0, 0, 0);
        #pragma unroll
        for (int r = 0; r < 4; ++r) {
            const int c = c0 + quad * 4 + r;
            #pragma unroll
            for (int cc = 0; cc < 2; ++cc) {
                size_t idx = (size_t)c * N_ + j0 + cc * 16 + l15;
                float ov = acc[cc][r] + bo[c];
                out_o[idx] = ov;
                out_y[idx] = 0.5f * ov + xb[idx];
            }
        }
    }
}

// ---------------------------------------------------------------------------
extern "C" void kernel_launch(void* const* d_in, const int* in_sizes, int n_in,
                              void* d_out, int out_size, void* d_ws, size_t ws_size,
                              hipStream_t stream)
{
    const float* x  = (const float*)d_in[0];
    const float* Wk = (const float*)d_in[1];
    const float* bk = (const float*)d_in[2];
    const float* Wq = (const float*)d_in[3];
    const float* bq = (const float*)d_in[4];
    const float* Wv = (const float*)d_in[5];
    const float* bv = (const float*)d_in[6];
    const float* Wo = (const float*)d_in[7];
    const float* bo = (const float*)d_in[8];
    float* out = (float*)d_out;

    char* ws = (char*)d_ws;
    _Float16* Qb    = (_Float16*)(ws);                   // 1 MB  [B][N][E]
    _Float16* Kb    = (_Float16*)(ws + (1u << 20));      // 1 MB  [B][N][E]
    _Float16* Vt    = (_Float16*)(ws + (2u << 20));      // 1 MB  [B][N/32][E][32]
    _Float16* Wof16 = (_Float16*)(ws + (3u << 20));      // 16 KB [C][E]

    // 512 proj blocks (n-tile 32, 2 blocks/CU; x read once)
    proj_kernel<<<dim3(512), dim3(256), 0, stream>>>(
        x, Wk, bk, Wq, bq, Wv, bv, Wo, Qb, Kb, Vt, Wof16, out);
    // 512 attn blocks: j-tile 32, KVBLK 64, 2 blocks/CU
    attn_kernel<<<dim3(B_ * (N_ / 32)), dim3(512), 0, stream>>>(
        Qb, Kb, Vt, Wof16, bo, x, out);
}